// Round 1
// baseline (4265.820 us; speedup 1.0000x reference)
//
#include <hip/hip_runtime.h>

// Problem constants (from reference):
// x: [50,16,2,640,360] f32, w_in: [100,460800], w_rec: [100,100], w_out: [6,100]
// out: voltages [50,16,6] f32
constexpr int TT = 50;
constexpr int BB = 16;
constexpr int HH = 100;
constexpr int OO = 6;
constexpr long long KK = 460800LL;   // F
constexpr int MM = TT * BB;          // 800

// ---------------- GEMM: xin[m][h] = sum_k x[m][k] * w_in[h][k] ----------------
// fp32 vector-ALU baseline (no fp32 MFMA on CDNA4). Split-K with atomicAdd.
constexpr int BM = 64;
constexpr int BK = 64;
constexpr int SPLITK = 48;
constexpr int KITERS = (int)(KK / (BK * SPLITK));  // 150
constexpr int XS_STRIDE = 68;  // padded, 4-aligned -> b128 LDS ok, conflicts benign
constexpr int WS_STRIDE = 68;

__global__ __launch_bounds__(256) void zero_f32(float* __restrict__ p, int n) {
    int i = blockIdx.x * 256 + threadIdx.x;
    if (i < n) p[i] = 0.0f;
}

__global__ __launch_bounds__(256) void gemm_xin(const float* __restrict__ x,
                                                const float* __restrict__ w,
                                                float* __restrict__ xin) {
    const int mtile = blockIdx.x;          // 0..12
    const int kchunk = blockIdx.y;         // 0..SPLITK-1
    const int row0 = mtile * BM;
    const long long k0 = (long long)kchunk * (long long)(KITERS * BK);

    __shared__ float XS[BM][XS_STRIDE];
    __shared__ float WS[HH][WS_STRIDE];

    const int tid = threadIdx.x;
    const int tx = tid & 15;   // row group: rows tx + 16*j, j=0..3
    const int ty = tid >> 4;   // col base:  cols ty + 16*jc, jc=0..6 (c<100)

    float acc[4][7];
#pragma unroll
    for (int j = 0; j < 4; ++j)
#pragma unroll
        for (int jc = 0; jc < 7; ++jc) acc[j][jc] = 0.0f;

    for (int kk = 0; kk < KITERS; ++kk) {
        const long long kbase = k0 + (long long)kk * BK;
        // ---- stage XS: 64 rows x 64 k (1024 float4, 4 per thread) ----
#pragma unroll
        for (int it = 0; it < 4; ++it) {
            int i = tid + it * 256;
            int r = i >> 4, kq = i & 15;
            int grow = row0 + r;
            float4 val = make_float4(0.f, 0.f, 0.f, 0.f);
            if (grow < MM)
                val = *(const float4*)(x + (long long)grow * KK + kbase + kq * 4);
            *(float4*)(&XS[r][kq * 4]) = val;
        }
        // ---- stage WS: 100 rows x 64 k (1600 float4) ----
        for (int i = tid; i < HH * 16; i += 256) {
            int c = i >> 4, kq = i & 15;
            float4 val = *(const float4*)(w + (long long)c * KK + kbase + kq * 4);
            *(float4*)(&WS[c][kq * 4]) = val;
        }
        __syncthreads();
        // ---- compute ----
        for (int k = 0; k < BK; k += 4) {
            float4 xa[4];
            float4 wb[7];
#pragma unroll
            for (int j = 0; j < 4; ++j)
                xa[j] = *(const float4*)(&XS[tx + 16 * j][k]);
#pragma unroll
            for (int jc = 0; jc < 7; ++jc) {
                int c = ty + 16 * jc;
                wb[jc] = (c < HH) ? *(const float4*)(&WS[c][k])
                                  : make_float4(0.f, 0.f, 0.f, 0.f);
            }
#pragma unroll
            for (int j = 0; j < 4; ++j)
#pragma unroll
                for (int jc = 0; jc < 7; ++jc) {
                    acc[j][jc] += xa[j].x * wb[jc].x;
                    acc[j][jc] += xa[j].y * wb[jc].y;
                    acc[j][jc] += xa[j].z * wb[jc].z;
                    acc[j][jc] += xa[j].w * wb[jc].w;
                }
        }
        __syncthreads();
    }
    // ---- split-K reduction ----
#pragma unroll
    for (int j = 0; j < 4; ++j) {
        int r = row0 + tx + 16 * j;
        if (r >= MM) continue;
#pragma unroll
        for (int jc = 0; jc < 7; ++jc) {
            int c = ty + 16 * jc;
            if (c < HH) atomicAdd(&xin[r * HH + c], acc[j][jc]);
        }
    }
}

// ---------------- Sequential scan: one block per batch element ----------------
// Constants folded: DT*TAU_MEM_INV=0.1, 1-DT*TAU_SYN_INV=0.9, V_TH=0.3,
// DT*LI_TAU_MEM_INV=0.1, 1-DT*LI_TAU_SYN_INV=0.8
__global__ __launch_bounds__(128) void scan_step(const float* __restrict__ xin,
                                                 const float* __restrict__ w_rec,
                                                 const float* __restrict__ w_out,
                                                 float* __restrict__ out) {
    const int b = blockIdx.x;
    const int tid = threadIdx.x;

    __shared__ float wrec_s[HH * 101];  // stride 101: 101 % 32 = 5, coprime -> no conflicts
    __shared__ float wout_s[OO * HH];
    __shared__ float zs[HH];

    for (int i = tid; i < HH * HH; i += 128) {
        int h = i / HH, h2 = i % HH;
        wrec_s[h * 101 + h2] = w_rec[i];
    }
    for (int i = tid; i < OO * HH; i += 128) wout_s[i] = w_out[i];
    if (tid < HH) zs[tid] = 0.0f;

    float v = 0.0f, icur = 0.0f;   // LIF state for hidden unit h = tid
    float vo = 0.0f, io = 0.0f;    // LI state for output o = tid (tid < 6)
    __syncthreads();

    for (int t = 0; t < TT; ++t) {
        float z_new = 0.0f;
        if (tid < HH) {
            // recurrent input uses z from previous step (zs not yet overwritten)
            float rec = 0.0f;
#pragma unroll 4
            for (int h2 = 0; h2 < HH; ++h2)
                rec += zs[h2] * wrec_s[tid * 101 + h2];
            float v_dec = v + 0.1f * (icur - v);
            float i_dec = 0.9f * icur;
            z_new = (v_dec - 0.3f) > 0.0f ? 1.0f : 0.0f;
            v = (1.0f - z_new) * v_dec;
            icur = i_dec + xin[t * (BB * HH) + b * HH + tid] + rec;
        }
        __syncthreads();               // all reads of old zs done
        if (tid < HH) zs[tid] = z_new; // publish new spikes
        __syncthreads();
        if (tid < OO) {
            float y = 0.0f;
#pragma unroll 4
            for (int h = 0; h < HH; ++h) y += zs[h] * wout_s[tid * HH + h];
            float vo_new = vo + 0.1f * (io - vo);  // uses old io
            io = 0.8f * io + y;
            out[t * (BB * OO) + b * OO + tid] = vo_new;
            vo = vo_new;
        }
    }
}

extern "C" void kernel_launch(void* const* d_in, const int* in_sizes, int n_in,
                              void* d_out, int out_size, void* d_ws, size_t ws_size,
                              hipStream_t stream) {
    const float* x = (const float*)d_in[0];
    const float* w_in = (const float*)d_in[1];
    const float* w_rec = (const float*)d_in[2];
    const float* w_out = (const float*)d_in[3];
    float* out = (float*)d_out;
    float* xin = (float*)d_ws;  // 800*100 f32 = 320 KB scratch

    const int xin_n = MM * HH;
    zero_f32<<<(xin_n + 255) / 256, 256, 0, stream>>>(xin, xin_n);

    dim3 grid((MM + BM - 1) / BM, SPLITK);  // 13 x 48 = 624 blocks
    gemm_xin<<<grid, 256, 0, stream>>>(x, w_in, xin);

    scan_step<<<BB, 128, 0, stream>>>(xin, w_rec, w_out, out);
}